// Round 2
// baseline (788.485 us; speedup 1.0000x reference)
//
#include <hip/hip_runtime.h>
#include <cstddef>

// Fixed problem instance (inputs are fp32 — probe-verified in r8: linear_f32
// executed full-length, reference setup_inputs is jnp.float32 throughout)
#define D_FEAT 128
static constexpr int N_NODES = 100000;
static constexpr int N_EDGES = 20000;
static constexpr int N_INC   = 800000;
static constexpr int N_CNT   = N_NODES + N_EDGES;          // combined histogram size
static constexpr int NBLK    = (N_CNT + 255) / 256;        // 469 scan blocks
static constexpr int N_WTILE = N_NODES / 16;               // 6250 16-row MFMA tiles

// Binned scatter geometry (r9): destination windows small enough to stay
// L2-resident so 4B bucket writes merge into full lines before eviction.
static constexpr int NB_SHIFT = 7;                          // 128 nodes / bin
static constexpr int EB_SHIFT = 5;                          // 32 edges / bin
static constexpr int N_NBIN   = (N_NODES + (1 << NB_SHIFT) - 1) >> NB_SHIFT; // 782
static constexpr int N_EBIN   = (N_EDGES + (1 << EB_SHIFT) - 1) >> EB_SHIFT; // 625
static constexpr int N_BIN    = N_NBIN + N_EBIN;            // 1407

typedef unsigned short u16;
typedef unsigned int   u32;
typedef __attribute__((ext_vector_type(8))) short v8s;     // MFMA A/B frag (8 bf16)
typedef __attribute__((ext_vector_type(4))) float v4f;     // MFMA C/D frag

// ---------------------------------------------------------------------------
__global__ __launch_bounds__(256) void zero_int(int* __restrict__ p, int n)
{
    int i = blockIdx.x * 256 + threadIdx.x;
    if (i < n) p[i] = 0;
}

// 1) combined degree histogram: cnt[node] and cnt[N_NODES+edge]
__global__ __launch_bounds__(256) void count_kernel(
    const int* __restrict__ ni, const int* __restrict__ ei,
    int* __restrict__ cnt)
{
    int i = blockIdx.x * 256 + threadIdx.x;
    if (i < N_INC) {
        atomicAdd(&cnt[ni[i]], 1);
        atomicAdd(&cnt[N_NODES + ei[i]], 1);
    }
}

// ---------------------------------------------------------------------------
// 2a) per-block exclusive scan of cnt -> cur (local), block totals -> bsum
__global__ __launch_bounds__(256) void scanA(
    const int* __restrict__ cnt, int* __restrict__ cur, int* __restrict__ bsum)
{
    __shared__ int s[256];
    const int tid = threadIdx.x;
    const int i = blockIdx.x * 256 + tid;
    int v = (i < N_CNT) ? cnt[i] : 0;
    s[tid] = v;
    __syncthreads();
    #pragma unroll
    for (int d = 1; d < 256; d <<= 1) {
        int t = (tid >= d) ? s[tid - d] : 0;
        __syncthreads();
        s[tid] += t;
        __syncthreads();
    }
    if (i < N_CNT) cur[i] = s[tid] - v;          // exclusive, block-local
    if (tid == 0) bsum[blockIdx.x] = s[255];     // block total
}

// 2b) single-block exclusive scan of bsum[NBLK]
__global__ __launch_bounds__(256) void scanB(int* __restrict__ a, int n)
{
    __shared__ int s[256];
    __shared__ int carry;
    const int tid = threadIdx.x;
    if (tid == 0) carry = 0;
    __syncthreads();
    for (int base = 0; base < n; base += 256) {
        int i = base + tid;
        int v = (i < n) ? a[i] : 0;
        s[tid] = v;
        __syncthreads();
        #pragma unroll
        for (int d = 1; d < 256; d <<= 1) {
            int t = (tid >= d) ? s[tid - d] : 0;
            __syncthreads();
            s[tid] += t;
            __syncthreads();
        }
        int excl = s[tid] - v + carry;
        int total = s[255];
        __syncthreads();
        if (tid == 0) carry += total;
        if (i < n) a[i] = excl;
        __syncthreads();
    }
}

// 2c) add block offsets
__global__ __launch_bounds__(256) void scanC(
    int* __restrict__ cur, const int* __restrict__ bsum)
{
    int i = blockIdx.x * 256 + threadIdx.x;
    if (i < N_CNT) cur[i] += bsum[blockIdx.x];
}

// ---------------------------------------------------------------------------
// 3a) bin cursors = scan value at each bin's boundary row (bins are contiguous
// ranges of node/edge ids, so cur[] already contains every bin start).
__global__ __launch_bounds__(256) void init_binpos(
    const int* __restrict__ cur, int* __restrict__ binPos)
{
    int b = blockIdx.x * 256 + threadIdx.x;
    if (b < N_NBIN)      binPos[b] = cur[b << NB_SHIFT];
    else if (b < N_BIN)  binPos[b] = cur[N_NODES + ((b - N_NBIN) << EB_SHIFT)];
}

// 3b) partition incidences into bins. Each bin's staged region is written
// sequentially (atomic cursor) -> L2 merges to full lines. Entry packs
// (edge,node) into 32 bits: e<2^15, n<2^17.
__global__ __launch_bounds__(256) void bin_stage(
    const int* __restrict__ ni, const int* __restrict__ ei,
    int* __restrict__ binPos, u32* __restrict__ stage_n, u32* __restrict__ stage_e)
{
    int i = blockIdx.x * 256 + threadIdx.x;
    if (i < N_INC) {
        int n = ni[i], e = ei[i];
        u32 p = ((u32)e << 17) | (u32)n;
        stage_n[atomicAdd(&binPos[n >> NB_SHIFT], 1)] = p;
        stage_e[atomicAdd(&binPos[N_NBIN + (e >> EB_SHIFT)], 1) - N_INC] = p;
    }
}

// 3c) scatter within each bin's ~4-5 KB destination window (one WG per bin;
// window + its cur counters stay resident in that WG's XCD L2 -> full-line
// evictions, ~16x less write traffic than the old global fill).
// Leaves cur as end-offsets (same contract as before for n2e/e2n).
__global__ __launch_bounds__(256) void bin_scatter(
    const int* __restrict__ binPos,
    const u32* __restrict__ stage_n, const u32* __restrict__ stage_e,
    int* __restrict__ cur, int* __restrict__ bkt_n, int* __restrict__ bkt_e)
{
    const int b = blockIdx.x;
    if (b < N_NBIN) {
        const int start = (b == 0) ? 0 : binPos[b - 1];      // ends are starts of next
        const int end   = binPos[b];
        for (int j = start + threadIdx.x; j < end; j += 256) {
            u32 p = stage_n[j];
            int n = (int)(p & 0x1FFFFu);
            int e = (int)(p >> 17);
            bkt_n[atomicAdd(&cur[n], 1)] = e;
        }
    } else {
        const int eb    = b - N_NBIN;
        const int start = (eb == 0) ? N_INC : binPos[b - 1];
        const int end   = binPos[b];
        for (int j = start + threadIdx.x; j < end; j += 256) {
            u32 p = stage_e[j - N_INC];
            int n = (int)(p & 0x1FFFFu);
            int e = (int)(p >> 17);
            bkt_e[atomicAdd(&cur[N_NODES + e], 1) - N_INC] = n;
        }
    }
}

// ---------------------------------------------------------------------------
// 4a) Dekker split: v = bf16(hi) + bf16(lo) with residual ~2^-17 rel.
__global__ __launch_bounds__(256) void split_kernel(
    const float* __restrict__ in, u16* __restrict__ hi, u16* __restrict__ lo, int n)
{
    for (int i = blockIdx.x * 256 + threadIdx.x; i < n; i += gridDim.x * 256) {
        float v = in[i];
        u32 uv = __float_as_uint(v);
        u32 h  = (uv + 0x7FFFu + ((uv >> 16) & 1u)) & 0xFFFF0000u;   // bf16 RNE
        float r = v - __uint_as_float(h);                            // exact
        u32 ur = __float_as_uint(r);
        u32 l  = ur + 0x7FFFu + ((ur >> 16) & 1u);
        hi[i] = (u16)(h >> 16);
        lo[i] = (u16)(l >> 16);
    }
}

// ---------------------------------------------------------------------------
// 4b) xn = (x @ W^T + b) * rsqrt(deg_n), fp32-accurate via split-bf16 MFMA:
// x.W^T = xhi.Whi + xhi.Wlo + xlo.Whi  (lo.lo ~2^-18, dropped).
// Wave tile 16 rows x 128 cols; A-frag lane(m,quad) = x[rowBase+m][k0..k0+7],
// B-frag = W[t*16+m][k0..k0+7] (gemm_bt pattern); C/D col=lane&15, row=quad*4+reg.
__global__ __launch_bounds__(256) void linear_mfma(
    const u16* __restrict__ xhi, const u16* __restrict__ xlo,
    const u16* __restrict__ Whi, const u16* __restrict__ Wlo,
    const float* __restrict__ bias, const int* __restrict__ cnt,
    float* __restrict__ xn)
{
    const int wave = threadIdx.x >> 6;
    const int lane = threadIdx.x & 63;
    const int rowBase = (blockIdx.x * 4 + wave) * 16;
    if (rowBase >= N_NODES) return;                 // tail waves idle (no barriers)
    const int m    = lane & 15;
    const int quad = lane >> 4;

    v4f acc[8];
    #pragma unroll
    for (int t = 0; t < 8; ++t) acc[t] = (v4f){0.f, 0.f, 0.f, 0.f};

    #pragma unroll
    for (int ks = 0; ks < 4; ++ks) {
        const int k0 = ks * 32 + quad * 8;
        const size_t axo = (size_t)(rowBase + m) * D_FEAT + k0;
        v8s ah = *(const v8s*)(xhi + axo);
        v8s al = *(const v8s*)(xlo + axo);
        #pragma unroll
        for (int t = 0; t < 8; ++t) {
            const size_t bo = (size_t)(t * 16 + m) * D_FEAT + k0;
            v8s bh = *(const v8s*)(Whi + bo);
            v8s bl = *(const v8s*)(Wlo + bo);
            acc[t] = __builtin_amdgcn_mfma_f32_16x16x32_bf16(ah, bh, acc[t], 0, 0, 0);
            acc[t] = __builtin_amdgcn_mfma_f32_16x16x32_bf16(ah, bl, acc[t], 0, 0, 0);
            acc[t] = __builtin_amdgcn_mfma_f32_16x16x32_bf16(al, bh, acc[t], 0, 0, 0);
        }
    }

    const int rq = rowBase + quad * 4;
    const int c0 = cnt[rq + 0], c1 = cnt[rq + 1], c2 = cnt[rq + 2], c3 = cnt[rq + 3];
    const float s0 = (c0 > 0) ? rsqrtf((float)c0) : 0.f;
    const float s1 = (c1 > 0) ? rsqrtf((float)c1) : 0.f;
    const float s2 = (c2 > 0) ? rsqrtf((float)c2) : 0.f;
    const float s3 = (c3 > 0) ? rsqrtf((float)c3) : 0.f;

    #pragma unroll
    for (int t = 0; t < 8; ++t) {
        const int col = t * 16 + m;
        const float bv = bias[col];
        float* o = xn + (size_t)rq * D_FEAT + col;
        o[0 * D_FEAT] = (acc[t][0] + bv) * s0;
        o[1 * D_FEAT] = (acc[t][1] + bv) * s1;
        o[2 * D_FEAT] = (acc[t][2] + bv) * s2;
        o[3 * D_FEAT] = (acc[t][3] + bv) * s3;
    }
}

// ---------------------------------------------------------------------------
// 5) per-edge gather: ef[e,:] = (1/|e|) * sum_{n in e} xn[n,:]
__global__ __launch_bounds__(256) void n2e_kernel(
    const int* __restrict__ cnt, const int* __restrict__ cur,
    const int* __restrict__ bkt_e, const float* __restrict__ xn,
    float* __restrict__ ef)
{
    const int e    = blockIdx.x * 4 + (threadIdx.x >> 6);
    const int lane = threadIdx.x & 63;
    const int c    = cnt[N_NODES + e];
    if (c == 0) return;                              // row never read downstream
    const int start = cur[N_NODES + e] - c - N_INC;  // cur holds end offsets
    float a0 = 0.f, a1 = 0.f;
    for (int j = 0; j < c; ++j) {
        int n = bkt_e[start + j];                    // wave-broadcast (L1)
        a0 += xn[(size_t)n * D_FEAT + lane];
        a1 += xn[(size_t)n * D_FEAT + 64 + lane];
    }
    float inv = 1.0f / (float)c;
    ef[(size_t)e * D_FEAT + lane]      = a0 * inv;
    ef[(size_t)e * D_FEAT + 64 + lane] = a1 * inv;
}

// ---------------------------------------------------------------------------
// 6) per-node gather + finalize: out[n,:] = relu(rsqrt(deg_n) * sum_e ef[e,:])
__global__ __launch_bounds__(256) void e2n_kernel(
    const int* __restrict__ cnt, const int* __restrict__ cur,
    const int* __restrict__ bkt_n, const float* __restrict__ ef,
    float* __restrict__ out)
{
    const int node = blockIdx.x * 4 + (threadIdx.x >> 6);   // 25000*4 == N_NODES
    const int lane = threadIdx.x & 63;
    const int c    = cnt[node];
    const int start = cur[node] - c;
    float a0 = 0.f, a1 = 0.f;
    for (int j = 0; j < c; ++j) {
        int e = bkt_n[start + j];                    // wave-broadcast (L1)
        a0 += ef[(size_t)e * D_FEAT + lane];
        a1 += ef[(size_t)e * D_FEAT + 64 + lane];
    }
    float s = (c > 0) ? rsqrtf((float)c) : 0.f;
    a0 *= s; a1 *= s;
    out[(size_t)node * D_FEAT + lane]      = (a0 > 0.f) ? a0 : 0.f;
    out[(size_t)node * D_FEAT + 64 + lane] = (a1 > 0.f) ? a1 : 0.f;
}

// ---------------------------------------------------------------------------
extern "C" void kernel_launch(void* const* d_in, const int* in_sizes, int n_in,
                              void* d_out, int out_size, void* d_ws, size_t ws_size,
                              hipStream_t stream)
{
    const float* x  = (const float*)d_in[0];   // fp32 (N,128)
    const float* W  = (const float*)d_in[1];   // fp32 (128,128)
    const float* b  = (const float*)d_in[2];   // fp32 (128,)
    const int* ni   = (const int*)d_in[3];     // (800000,) node_idx
    const int* ei   = (const int*)d_in[4];     // (800000,) edge_idx
    float* out = (float*)d_out;                // fp32 (N,128)

    // Workspace (~58.6 MB; r1 proved >=61.9 MB available).
    // Region A (51.2 MB): bin staging (6.4 MB) lives here FIRST, then dies;
    // split writes xhi/xlo here; ef aliases it after the linear.
    char* base = (char*)d_ws;
    u16*   xhi  = (u16*)base;                                  // 25.6 MB
    u16*   xlo  = (u16*)(base + (size_t)N_NODES * D_FEAT * 2); // 25.6 MB
    float* ef   = (float*)base;                                // aliases region A
    u32* stage_n = (u32*)base;                                 // aliases region A
    u32* stage_e = (u32*)(base + (size_t)N_INC * 4);           // aliases region A
    char* p = base + (size_t)N_NODES * D_FEAT * 4;             // end of region A
    int* cnt    = (int*)p;   p += (size_t)N_CNT * 4;
    int* cur    = (int*)p;   p += (size_t)N_CNT * 4;
    int* bsum   = (int*)p;   p += (size_t)((NBLK + 7) & ~7) * 4;
    u16* Whi    = (u16*)p;   p += (size_t)D_FEAT * D_FEAT * 2; // 32 KB
    u16* Wlo    = (u16*)p;   p += (size_t)D_FEAT * D_FEAT * 2; // 32 KB
    int* binPos = (int*)p;   p += (size_t)((N_BIN + 7) & ~7) * 4; // 5.6 KB
    int* bkt_n  = (int*)p;   p += (size_t)N_INC * 4;           // 3.2 MB
    int* bkt_e  = (int*)p;   p += (size_t)N_INC * 4;           // 3.2 MB
    float* xn   = out;   // xn staged in d_out (linear writes, n2e reads, e2n overwrites)

    const int nInc = (N_INC + 255) / 256;

    zero_int<<<NBLK, 256, 0, stream>>>(cnt, N_CNT);
    count_kernel<<<nInc, 256, 0, stream>>>(ni, ei, cnt);

    scanA<<<NBLK, 256, 0, stream>>>(cnt, cur, bsum);
    scanB<<<1, 256, 0, stream>>>(bsum, NBLK);
    scanC<<<NBLK, 256, 0, stream>>>(cur, bsum);

    // binned CSR fill (replaces the old single-pass random scatter fill)
    init_binpos<<<(N_BIN + 255) / 256, 256, 0, stream>>>(cur, binPos);
    bin_stage<<<nInc, 256, 0, stream>>>(ni, ei, binPos, stage_n, stage_e);
    bin_scatter<<<N_BIN, 256, 0, stream>>>(binPos, stage_n, stage_e,
                                           cur, bkt_n, bkt_e);

    // split AFTER scatter: staging aliased region A
    split_kernel<<<1024, 256, 0, stream>>>(x, xhi, xlo, N_NODES * D_FEAT);
    split_kernel<<<64, 256, 0, stream>>>(W, Whi, Wlo, D_FEAT * D_FEAT);

    linear_mfma<<<(N_WTILE + 3) / 4, 256, 0, stream>>>(
        xhi, xlo, Whi, Wlo, b, cnt, xn);

    n2e_kernel<<<N_EDGES / 4, 256, 0, stream>>>(cnt, cur, bkt_e, xn, ef);

    e2n_kernel<<<N_NODES / 4, 256, 0, stream>>>(cnt, cur, bkt_n, ef, out);
}

// Round 3
// 640.674 us; speedup vs baseline: 1.2307x; 1.2307x over previous
//
#include <hip/hip_runtime.h>
#include <cstddef>

// Fixed problem instance (inputs are fp32 — probe-verified in r8: linear_f32
// executed full-length, reference setup_inputs is jnp.float32 throughout)
#define D_FEAT 128
static constexpr int N_NODES = 100000;
static constexpr int N_EDGES = 20000;
static constexpr int N_INC   = 800000;
static constexpr int N_CNT   = N_NODES + N_EDGES;          // combined histogram size
static constexpr int NBLK    = (N_CNT + 255) / 256;        // 469 scan blocks
static constexpr int N_WTILE = N_NODES / 16;               // 6250 16-row MFMA tiles

// Binned scatter geometry. r9 post-mortem: 1407 bins -> ~1100 atomic-return
// hits per binPos counter -> cross-XCD ownership ping-pong serialized
// bin_stage at 300us (HBM 3%, VALU 0.1%). r10: 16x more bins spreads the
// contention (~70 hits/counter); count_kernel proves 1.6M atomics over many
// addresses are cheap. Windows shrink to ~64-80 elems -> one wave per bin.
static constexpr int NB_SHIFT = 3;                          // 8 nodes / bin
static constexpr int EB_SHIFT = 1;                          // 2 edges / bin
static constexpr int N_NBIN   = N_NODES >> NB_SHIFT;        // 12500 (exact)
static constexpr int N_EBIN   = N_EDGES >> EB_SHIFT;        // 10000 (exact)
static constexpr int N_BIN    = N_NBIN + N_EBIN;            // 22500

typedef unsigned short u16;
typedef unsigned int   u32;
typedef __attribute__((ext_vector_type(8))) short v8s;     // MFMA A/B frag (8 bf16)
typedef __attribute__((ext_vector_type(4))) float v4f;     // MFMA C/D frag

// ---------------------------------------------------------------------------
__global__ __launch_bounds__(256) void zero_int(int* __restrict__ p, int n)
{
    int i = blockIdx.x * 256 + threadIdx.x;
    if (i < n) p[i] = 0;
}

// 1) combined degree histogram: cnt[node] and cnt[N_NODES+edge]
__global__ __launch_bounds__(256) void count_kernel(
    const int* __restrict__ ni, const int* __restrict__ ei,
    int* __restrict__ cnt)
{
    int i = blockIdx.x * 256 + threadIdx.x;
    if (i < N_INC) {
        atomicAdd(&cnt[ni[i]], 1);
        atomicAdd(&cnt[N_NODES + ei[i]], 1);
    }
}

// ---------------------------------------------------------------------------
// 2a) per-block exclusive scan of cnt -> cur (local), block totals -> bsum
__global__ __launch_bounds__(256) void scanA(
    const int* __restrict__ cnt, int* __restrict__ cur, int* __restrict__ bsum)
{
    __shared__ int s[256];
    const int tid = threadIdx.x;
    const int i = blockIdx.x * 256 + tid;
    int v = (i < N_CNT) ? cnt[i] : 0;
    s[tid] = v;
    __syncthreads();
    #pragma unroll
    for (int d = 1; d < 256; d <<= 1) {
        int t = (tid >= d) ? s[tid - d] : 0;
        __syncthreads();
        s[tid] += t;
        __syncthreads();
    }
    if (i < N_CNT) cur[i] = s[tid] - v;          // exclusive, block-local
    if (tid == 0) bsum[blockIdx.x] = s[255];     // block total
}

// 2b) single-block exclusive scan of bsum[NBLK]
__global__ __launch_bounds__(256) void scanB(int* __restrict__ a, int n)
{
    __shared__ int s[256];
    __shared__ int carry;
    const int tid = threadIdx.x;
    if (tid == 0) carry = 0;
    __syncthreads();
    for (int base = 0; base < n; base += 256) {
        int i = base + tid;
        int v = (i < n) ? a[i] : 0;
        s[tid] = v;
        __syncthreads();
        #pragma unroll
        for (int d = 1; d < 256; d <<= 1) {
            int t = (tid >= d) ? s[tid - d] : 0;
            __syncthreads();
            s[tid] += t;
            __syncthreads();
        }
        int excl = s[tid] - v + carry;
        int total = s[255];
        __syncthreads();
        if (tid == 0) carry += total;
        if (i < n) a[i] = excl;
        __syncthreads();
    }
}

// 2c) add block offsets
__global__ __launch_bounds__(256) void scanC(
    int* __restrict__ cur, const int* __restrict__ bsum)
{
    int i = blockIdx.x * 256 + threadIdx.x;
    if (i < N_CNT) cur[i] += bsum[blockIdx.x];
}

// ---------------------------------------------------------------------------
// 3a) bin cursors = scan value at each bin's boundary row (bins are contiguous
// ranges of node/edge ids, so cur[] already contains every bin start).
__global__ __launch_bounds__(256) void init_binpos(
    const int* __restrict__ cur, int* __restrict__ binPos)
{
    int b = blockIdx.x * 256 + threadIdx.x;
    if (b < N_NBIN)      binPos[b] = cur[b << NB_SHIFT];
    else if (b < N_BIN)  binPos[b] = cur[N_NODES + ((b - N_NBIN) << EB_SHIFT)];
}

// 3b) partition incidences into bins. Each bin's staged region is written
// sequentially (atomic cursor) -> frontier lines merge in L2. Entry packs
// (edge,node) into 32 bits: e<2^15, n<2^17.
__global__ __launch_bounds__(256) void bin_stage(
    const int* __restrict__ ni, const int* __restrict__ ei,
    int* __restrict__ binPos, u32* __restrict__ stage_n, u32* __restrict__ stage_e)
{
    int i = blockIdx.x * 256 + threadIdx.x;
    if (i < N_INC) {
        int n = ni[i], e = ei[i];
        u32 p = ((u32)e << 17) | (u32)n;
        stage_n[atomicAdd(&binPos[n >> NB_SHIFT], 1)] = p;
        stage_e[atomicAdd(&binPos[N_NBIN + (e >> EB_SHIFT)], 1) - N_INC] = p;
    }
}

// 3c) scatter within each bin's <=~320B destination window (one WAVE per bin,
// 4 bins per block; window + its cur counters are touched by exactly one
// workgroup -> stay L2-resident -> full-line evictions).
// Leaves cur as end-offsets (same contract as before for n2e/e2n).
__global__ __launch_bounds__(256) void bin_scatter(
    const int* __restrict__ binPos,
    const u32* __restrict__ stage_n, const u32* __restrict__ stage_e,
    int* __restrict__ cur, int* __restrict__ bkt_n, int* __restrict__ bkt_e)
{
    const int b = blockIdx.x * 4 + (threadIdx.x >> 6);
    if (b >= N_BIN) return;
    const int lane = threadIdx.x & 63;
    if (b < N_NBIN) {
        const int start = (b == 0) ? 0 : binPos[b - 1];      // ends are starts of next
        const int end   = binPos[b];
        for (int j = start + lane; j < end; j += 64) {
            u32 p = stage_n[j];
            bkt_n[atomicAdd(&cur[p & 0x1FFFFu], 1)] = (int)(p >> 17);
        }
    } else {
        const int start = (b == N_NBIN) ? N_INC : binPos[b - 1];
        const int end   = binPos[b];
        for (int j = start + lane; j < end; j += 64) {
            u32 p = stage_e[j - N_INC];
            bkt_e[atomicAdd(&cur[N_NODES + (p >> 17)], 1) - N_INC] = (int)(p & 0x1FFFFu);
        }
    }
}

// ---------------------------------------------------------------------------
// 4a) Dekker split: v = bf16(hi) + bf16(lo) with residual ~2^-17 rel.
__global__ __launch_bounds__(256) void split_kernel(
    const float* __restrict__ in, u16* __restrict__ hi, u16* __restrict__ lo, int n)
{
    for (int i = blockIdx.x * 256 + threadIdx.x; i < n; i += gridDim.x * 256) {
        float v = in[i];
        u32 uv = __float_as_uint(v);
        u32 h  = (uv + 0x7FFFu + ((uv >> 16) & 1u)) & 0xFFFF0000u;   // bf16 RNE
        float r = v - __uint_as_float(h);                            // exact
        u32 ur = __float_as_uint(r);
        u32 l  = ur + 0x7FFFu + ((ur >> 16) & 1u);
        hi[i] = (u16)(h >> 16);
        lo[i] = (u16)(l >> 16);
    }
}

// ---------------------------------------------------------------------------
// 4b) xn = (x @ W^T + b) * rsqrt(deg_n), fp32-accurate via split-bf16 MFMA:
// x.W^T = xhi.Whi + xhi.Wlo + xlo.Whi  (lo.lo ~2^-18, dropped).
// Wave tile 16 rows x 128 cols; A-frag lane(m,quad) = x[rowBase+m][k0..k0+7],
// B-frag = W[t*16+m][k0..k0+7] (gemm_bt pattern); C/D col=lane&15, row=quad*4+reg.
__global__ __launch_bounds__(256) void linear_mfma(
    const u16* __restrict__ xhi, const u16* __restrict__ xlo,
    const u16* __restrict__ Whi, const u16* __restrict__ Wlo,
    const float* __restrict__ bias, const int* __restrict__ cnt,
    float* __restrict__ xn)
{
    const int wave = threadIdx.x >> 6;
    const int lane = threadIdx.x & 63;
    const int rowBase = (blockIdx.x * 4 + wave) * 16;
    if (rowBase >= N_NODES) return;                 // tail waves idle (no barriers)
    const int m    = lane & 15;
    const int quad = lane >> 4;

    v4f acc[8];
    #pragma unroll
    for (int t = 0; t < 8; ++t) acc[t] = (v4f){0.f, 0.f, 0.f, 0.f};

    #pragma unroll
    for (int ks = 0; ks < 4; ++ks) {
        const int k0 = ks * 32 + quad * 8;
        const size_t axo = (size_t)(rowBase + m) * D_FEAT + k0;
        v8s ah = *(const v8s*)(xhi + axo);
        v8s al = *(const v8s*)(xlo + axo);
        #pragma unroll
        for (int t = 0; t < 8; ++t) {
            const size_t bo = (size_t)(t * 16 + m) * D_FEAT + k0;
            v8s bh = *(const v8s*)(Whi + bo);
            v8s bl = *(const v8s*)(Wlo + bo);
            acc[t] = __builtin_amdgcn_mfma_f32_16x16x32_bf16(ah, bh, acc[t], 0, 0, 0);
            acc[t] = __builtin_amdgcn_mfma_f32_16x16x32_bf16(ah, bl, acc[t], 0, 0, 0);
            acc[t] = __builtin_amdgcn_mfma_f32_16x16x32_bf16(al, bh, acc[t], 0, 0, 0);
        }
    }

    const int rq = rowBase + quad * 4;
    const int c0 = cnt[rq + 0], c1 = cnt[rq + 1], c2 = cnt[rq + 2], c3 = cnt[rq + 3];
    const float s0 = (c0 > 0) ? rsqrtf((float)c0) : 0.f;
    const float s1 = (c1 > 0) ? rsqrtf((float)c1) : 0.f;
    const float s2 = (c2 > 0) ? rsqrtf((float)c2) : 0.f;
    const float s3 = (c3 > 0) ? rsqrtf((float)c3) : 0.f;

    #pragma unroll
    for (int t = 0; t < 8; ++t) {
        const int col = t * 16 + m;
        const float bv = bias[col];
        float* o = xn + (size_t)rq * D_FEAT + col;
        o[0 * D_FEAT] = (acc[t][0] + bv) * s0;
        o[1 * D_FEAT] = (acc[t][1] + bv) * s1;
        o[2 * D_FEAT] = (acc[t][2] + bv) * s2;
        o[3 * D_FEAT] = (acc[t][3] + bv) * s3;
    }
}

// ---------------------------------------------------------------------------
// 5) per-edge gather: ef[e,:] = (1/|e|) * sum_{n in e} xn[n,:]
__global__ __launch_bounds__(256) void n2e_kernel(
    const int* __restrict__ cnt, const int* __restrict__ cur,
    const int* __restrict__ bkt_e, const float* __restrict__ xn,
    float* __restrict__ ef)
{
    const int e    = blockIdx.x * 4 + (threadIdx.x >> 6);
    const int lane = threadIdx.x & 63;
    const int c    = cnt[N_NODES + e];
    if (c == 0) return;                              // row never read downstream
    const int start = cur[N_NODES + e] - c - N_INC;  // cur holds end offsets
    float a0 = 0.f, a1 = 0.f;
    for (int j = 0; j < c; ++j) {
        int n = bkt_e[start + j];                    // wave-broadcast (L1)
        a0 += xn[(size_t)n * D_FEAT + lane];
        a1 += xn[(size_t)n * D_FEAT + 64 + lane];
    }
    float inv = 1.0f / (float)c;
    ef[(size_t)e * D_FEAT + lane]      = a0 * inv;
    ef[(size_t)e * D_FEAT + 64 + lane] = a1 * inv;
}

// ---------------------------------------------------------------------------
// 6) per-node gather + finalize: out[n,:] = relu(rsqrt(deg_n) * sum_e ef[e,:])
__global__ __launch_bounds__(256) void e2n_kernel(
    const int* __restrict__ cnt, const int* __restrict__ cur,
    const int* __restrict__ bkt_n, const float* __restrict__ ef,
    float* __restrict__ out)
{
    const int node = blockIdx.x * 4 + (threadIdx.x >> 6);   // 25000*4 == N_NODES
    const int lane = threadIdx.x & 63;
    const int c    = cnt[node];
    const int start = cur[node] - c;
    float a0 = 0.f, a1 = 0.f;
    for (int j = 0; j < c; ++j) {
        int e = bkt_n[start + j];                    // wave-broadcast (L1)
        a0 += ef[(size_t)e * D_FEAT + lane];
        a1 += ef[(size_t)e * D_FEAT + 64 + lane];
    }
    float s = (c > 0) ? rsqrtf((float)c) : 0.f;
    a0 *= s; a1 *= s;
    out[(size_t)node * D_FEAT + lane]      = (a0 > 0.f) ? a0 : 0.f;
    out[(size_t)node * D_FEAT + 64 + lane] = (a1 > 0.f) ? a1 : 0.f;
}

// ---------------------------------------------------------------------------
extern "C" void kernel_launch(void* const* d_in, const int* in_sizes, int n_in,
                              void* d_out, int out_size, void* d_ws, size_t ws_size,
                              hipStream_t stream)
{
    const float* x  = (const float*)d_in[0];   // fp32 (N,128)
    const float* W  = (const float*)d_in[1];   // fp32 (128,128)
    const float* b  = (const float*)d_in[2];   // fp32 (128,)
    const int* ni   = (const int*)d_in[3];     // (800000,) node_idx
    const int* ei   = (const int*)d_in[4];     // (800000,) edge_idx
    float* out = (float*)d_out;                // fp32 (N,128)

    // Workspace (~58.7 MB; r1 proved >=61.9 MB available).
    // Region A (51.2 MB): bin staging (6.4 MB) lives here FIRST, then dies;
    // split writes xhi/xlo here; ef aliases it after the linear.
    char* base = (char*)d_ws;
    u16*   xhi  = (u16*)base;                                  // 25.6 MB
    u16*   xlo  = (u16*)(base + (size_t)N_NODES * D_FEAT * 2); // 25.6 MB
    float* ef   = (float*)base;                                // aliases region A
    u32* stage_n = (u32*)base;                                 // aliases region A
    u32* stage_e = (u32*)(base + (size_t)N_INC * 4);           // aliases region A
    char* p = base + (size_t)N_NODES * D_FEAT * 4;             // end of region A
    int* cnt    = (int*)p;   p += (size_t)N_CNT * 4;
    int* cur    = (int*)p;   p += (size_t)N_CNT * 4;
    int* bsum   = (int*)p;   p += (size_t)((NBLK + 7) & ~7) * 4;
    u16* Whi    = (u16*)p;   p += (size_t)D_FEAT * D_FEAT * 2; // 32 KB
    u16* Wlo    = (u16*)p;   p += (size_t)D_FEAT * D_FEAT * 2; // 32 KB
    int* binPos = (int*)p;   p += (size_t)((N_BIN + 7) & ~7) * 4; // 90 KB
    int* bkt_n  = (int*)p;   p += (size_t)N_INC * 4;           // 3.2 MB
    int* bkt_e  = (int*)p;   p += (size_t)N_INC * 4;           // 3.2 MB
    float* xn   = out;   // xn staged in d_out (linear writes, n2e reads, e2n overwrites)

    const int nInc = (N_INC + 255) / 256;

    zero_int<<<NBLK, 256, 0, stream>>>(cnt, N_CNT);
    count_kernel<<<nInc, 256, 0, stream>>>(ni, ei, cnt);

    scanA<<<NBLK, 256, 0, stream>>>(cnt, cur, bsum);
    scanB<<<1, 256, 0, stream>>>(bsum, NBLK);
    scanC<<<NBLK, 256, 0, stream>>>(cur, bsum);

    // binned CSR fill (r10: 22500 bins to kill binPos atomic contention)
    init_binpos<<<(N_BIN + 255) / 256, 256, 0, stream>>>(cur, binPos);
    bin_stage<<<nInc, 256, 0, stream>>>(ni, ei, binPos, stage_n, stage_e);
    bin_scatter<<<(N_BIN + 3) / 4, 256, 0, stream>>>(binPos, stage_n, stage_e,
                                                     cur, bkt_n, bkt_e);

    // split AFTER scatter: staging aliased region A
    split_kernel<<<1024, 256, 0, stream>>>(x, xhi, xlo, N_NODES * D_FEAT);
    split_kernel<<<64, 256, 0, stream>>>(W, Whi, Wlo, D_FEAT * D_FEAT);

    linear_mfma<<<(N_WTILE + 3) / 4, 256, 0, stream>>>(
        xhi, xlo, Whi, Wlo, b, cnt, xn);

    n2e_kernel<<<N_EDGES / 4, 256, 0, stream>>>(cnt, cur, bkt_e, xn, ef);

    e2n_kernel<<<N_NODES / 4, 256, 0, stream>>>(cnt, cur, bkt_n, ef, out);
}

// Round 4
// 570.353 us; speedup vs baseline: 1.3825x; 1.1233x over previous
//
#include <hip/hip_runtime.h>
#include <cstddef>

// Fixed problem instance (inputs fp32; probe-verified r8)
#define D_FEAT 128
static constexpr int N_NODES = 100000;
static constexpr int N_EDGES = 20000;
static constexpr int N_INC   = 800000;
static constexpr int N_WTILE = N_NODES / 16;               // 6250 16-row MFMA tiles

// r11: sliced staged-CSR. r10 post-mortem: stage WRITE_SIZE stayed ~96MB
// (1.6M x 64B) because each bin frontier line is written from all 8 XCDs ->
// partial-line eviction per ownership migration. Fix: per-(bin,slice)
// segments with slice = blockIdx%8 (empirical round-robin block->XCD);
// each slice's write window is single-XCD -> lines fill before eviction.
// Consume kernels read staged (e,n) segments directly -> the bkt arrays,
// bin_scatter pass and 120K-entity scan are deleted.
static constexpr int NSLC    = 8;
static constexpr int NB_SHIFT= 1;                           // 2 nodes / bin
static constexpr int N_NBIN  = N_NODES >> NB_SHIFT;         // 50000
static constexpr int NS_CNT  = NSLC * N_NBIN;               // 400000 node-side counters
static constexpr int ES_CNT  = NSLC * N_EDGES;              // 160000 edge-side counters
static constexpr int BS_TOTAL= NS_CNT + ES_CNT;             // 560000
static constexpr int NBLK2   = (BS_TOTAL + 255) / 256;      // 2188 scan blocks
static constexpr int N_STAGE = 2 * N_INC;                   // 1.6M staged entries

typedef unsigned short u16;
typedef unsigned int   u32;
typedef __attribute__((ext_vector_type(8))) short v8s;     // MFMA A/B frag (8 bf16)
typedef __attribute__((ext_vector_type(4))) float v4f;     // MFMA C/D frag

// ---------------------------------------------------------------------------
__global__ __launch_bounds__(256) void zero_int(int* __restrict__ p, int n)
{
    int i = blockIdx.x * 256 + threadIdx.x;
    if (i < n) p[i] = 0;
}

// 1) histogram: per-node degree (for rsqrt) + per-(bin,slice) counts.
// Per-edge degree is NOT counted: n2e derives |e| from its segment bounds.
__global__ __launch_bounds__(256) void count2(
    const int* __restrict__ ni, const int* __restrict__ ei,
    int* __restrict__ cnt_n, int* __restrict__ bs)
{
    int i = blockIdx.x * 256 + threadIdx.x;
    int s = blockIdx.x & 7;                       // must match stage2's mapping
    if (i < N_INC) {
        int n = ni[i], e = ei[i];
        atomicAdd(&cnt_n[n], 1);
        atomicAdd(&bs[s * N_NBIN + (n >> NB_SHIFT)], 1);
        atomicAdd(&bs[NS_CNT + s * N_EDGES + e], 1);
    }
}

// ---------------------------------------------------------------------------
// 2a) per-block exclusive scan IN PLACE (reads then writes same array)
__global__ __launch_bounds__(256) void scanA(
    int* __restrict__ a, int* __restrict__ bsum, int n)
{
    __shared__ int sm[256];
    const int tid = threadIdx.x;
    const int i = blockIdx.x * 256 + tid;
    int v = (i < n) ? a[i] : 0;
    sm[tid] = v;
    __syncthreads();
    #pragma unroll
    for (int d = 1; d < 256; d <<= 1) {
        int t = (tid >= d) ? sm[tid - d] : 0;
        __syncthreads();
        sm[tid] += t;
        __syncthreads();
    }
    if (i < n) a[i] = sm[tid] - v;               // exclusive, block-local
    if (tid == 0) bsum[blockIdx.x] = sm[255];    // block total
}

// 2b) single-block exclusive scan of bsum[n]
__global__ __launch_bounds__(256) void scanB(int* __restrict__ a, int n)
{
    __shared__ int sm[256];
    __shared__ int carry;
    const int tid = threadIdx.x;
    if (tid == 0) carry = 0;
    __syncthreads();
    for (int base = 0; base < n; base += 256) {
        int i = base + tid;
        int v = (i < n) ? a[i] : 0;
        sm[tid] = v;
        __syncthreads();
        #pragma unroll
        for (int d = 1; d < 256; d <<= 1) {
            int t = (tid >= d) ? sm[tid - d] : 0;
            __syncthreads();
            sm[tid] += t;
            __syncthreads();
        }
        int excl = sm[tid] - v + carry;
        int total = sm[255];
        __syncthreads();
        if (tid == 0) carry += total;
        if (i < n) a[i] = excl;
        __syncthreads();
    }
}

// 2c) add block offsets in place
__global__ __launch_bounds__(256) void scanC(
    int* __restrict__ a, const int* __restrict__ bsum, int n)
{
    int i = blockIdx.x * 256 + threadIdx.x;
    if (i < n) a[i] += bsum[blockIdx.x];
}

// ---------------------------------------------------------------------------
// 3) stage: write packed (e,n) into per-(bin,slice) segments. Same grid and
// slice mapping as count2 so cursor arithmetic matches. After this kernel,
// bs[k] = end of segment k = start of segment k+1 (exclusive-scan property),
// so consume kernels need no pristine copy of the offsets.
__global__ __launch_bounds__(256) void stage2(
    const int* __restrict__ ni, const int* __restrict__ ei,
    int* __restrict__ bs, u32* __restrict__ stage)
{
    int i = blockIdx.x * 256 + threadIdx.x;
    int s = blockIdx.x & 7;
    if (i < N_INC) {
        int n = ni[i], e = ei[i];
        u32 p = ((u32)e << 17) | (u32)n;          // e<2^15, n<2^17
        stage[atomicAdd(&bs[s * N_NBIN + (n >> NB_SHIFT)], 1)] = p;
        stage[atomicAdd(&bs[NS_CNT + s * N_EDGES + e], 1)] = p;
    }
}

// ---------------------------------------------------------------------------
// 4a) Dekker split: v = bf16(hi) + bf16(lo) with residual ~2^-17 rel.
__global__ __launch_bounds__(256) void split_kernel(
    const float* __restrict__ in, u16* __restrict__ hi, u16* __restrict__ lo, int n)
{
    for (int i = blockIdx.x * 256 + threadIdx.x; i < n; i += gridDim.x * 256) {
        float v = in[i];
        u32 uv = __float_as_uint(v);
        u32 h  = (uv + 0x7FFFu + ((uv >> 16) & 1u)) & 0xFFFF0000u;   // bf16 RNE
        float r = v - __uint_as_float(h);                            // exact
        u32 ur = __float_as_uint(r);
        u32 l  = ur + 0x7FFFu + ((ur >> 16) & 1u);
        hi[i] = (u16)(h >> 16);
        lo[i] = (u16)(l >> 16);
    }
}

// ---------------------------------------------------------------------------
// 4b) xn = (x @ W^T + b) * rsqrt(deg_n), fp32-accurate via split-bf16 MFMA:
// x.W^T = xhi.Whi + xhi.Wlo + xlo.Whi  (lo.lo ~2^-18, dropped).
// Wave tile 16 rows x 128 cols; gemm_bt fragment pattern; C/D col=lane&15,
// row=quad*4+reg.  (unchanged, proven)
__global__ __launch_bounds__(256) void linear_mfma(
    const u16* __restrict__ xhi, const u16* __restrict__ xlo,
    const u16* __restrict__ Whi, const u16* __restrict__ Wlo,
    const float* __restrict__ bias, const int* __restrict__ cnt_n,
    float* __restrict__ xn)
{
    const int wave = threadIdx.x >> 6;
    const int lane = threadIdx.x & 63;
    const int rowBase = (blockIdx.x * 4 + wave) * 16;
    if (rowBase >= N_NODES) return;                 // tail waves idle (no barriers)
    const int m    = lane & 15;
    const int quad = lane >> 4;

    v4f acc[8];
    #pragma unroll
    for (int t = 0; t < 8; ++t) acc[t] = (v4f){0.f, 0.f, 0.f, 0.f};

    #pragma unroll
    for (int ks = 0; ks < 4; ++ks) {
        const int k0 = ks * 32 + quad * 8;
        const size_t axo = (size_t)(rowBase + m) * D_FEAT + k0;
        v8s ah = *(const v8s*)(xhi + axo);
        v8s al = *(const v8s*)(xlo + axo);
        #pragma unroll
        for (int t = 0; t < 8; ++t) {
            const size_t bo = (size_t)(t * 16 + m) * D_FEAT + k0;
            v8s bh = *(const v8s*)(Whi + bo);
            v8s bl = *(const v8s*)(Wlo + bo);
            acc[t] = __builtin_amdgcn_mfma_f32_16x16x32_bf16(ah, bh, acc[t], 0, 0, 0);
            acc[t] = __builtin_amdgcn_mfma_f32_16x16x32_bf16(ah, bl, acc[t], 0, 0, 0);
            acc[t] = __builtin_amdgcn_mfma_f32_16x16x32_bf16(al, bh, acc[t], 0, 0, 0);
        }
    }

    const int rq = rowBase + quad * 4;
    const int c0 = cnt_n[rq + 0], c1 = cnt_n[rq + 1];
    const int c2 = cnt_n[rq + 2], c3 = cnt_n[rq + 3];
    const float s0 = (c0 > 0) ? rsqrtf((float)c0) : 0.f;
    const float s1 = (c1 > 0) ? rsqrtf((float)c1) : 0.f;
    const float s2 = (c2 > 0) ? rsqrtf((float)c2) : 0.f;
    const float s3 = (c3 > 0) ? rsqrtf((float)c3) : 0.f;

    #pragma unroll
    for (int t = 0; t < 8; ++t) {
        const int col = t * 16 + m;
        const float bv = bias[col];
        float* o = xn + (size_t)rq * D_FEAT + col;
        o[0 * D_FEAT] = (acc[t][0] + bv) * s0;
        o[1 * D_FEAT] = (acc[t][1] + bv) * s1;
        o[2 * D_FEAT] = (acc[t][2] + bv) * s2;
        o[3 * D_FEAT] = (acc[t][3] + bv) * s3;
    }
}

// ---------------------------------------------------------------------------
// 5) per-edge gather from staged segments: ef[e,:] = (1/|e|) * sum xn[n,:]
// One wave per edge; its entries live in 8 slice segments. |e| derived from
// segment bounds (no edge-degree array). bs[k-1] = final end of k-1 = start
// of k (valid for k>=1; first edge-side k is NS_CNT so k-1 is node-side last).
__global__ __launch_bounds__(256) void n2e2(
    const int* __restrict__ bs, const u32* __restrict__ stage,
    const float* __restrict__ xn, float* __restrict__ ef)
{
    const int e    = blockIdx.x * 4 + (threadIdx.x >> 6);
    const int lane = threadIdx.x & 63;
    float a0 = 0.f, a1 = 0.f;
    int c = 0;
    #pragma unroll
    for (int s = 0; s < NSLC; ++s) {
        const int k  = NS_CNT + s * N_EDGES + e;
        const int st = bs[k - 1];
        const int en = bs[k];
        c += en - st;
        for (int j = st; j < en; ++j) {
            int n = (int)(stage[j] & 0x1FFFFu);  // wave-broadcast (L1)
            a0 += xn[(size_t)n * D_FEAT + lane];
            a1 += xn[(size_t)n * D_FEAT + 64 + lane];
        }
    }
    const float inv = (c > 0) ? (1.0f / (float)c) : 0.f;
    ef[(size_t)e * D_FEAT + lane]      = a0 * inv;
    ef[(size_t)e * D_FEAT + 64 + lane] = a1 * inv;
}

// ---------------------------------------------------------------------------
// 6) per-node-bin gather + finalize. One wave per 2-node bin; entry's low bit
// (= n&1) selects the accumulator pair (wave-uniform branch).
__global__ __launch_bounds__(256) void e2n2(
    const int* __restrict__ bs, const u32* __restrict__ stage,
    const int* __restrict__ cnt_n, const float* __restrict__ ef,
    float* __restrict__ out)
{
    const int nb   = blockIdx.x * 4 + (threadIdx.x >> 6);   // 12500*4 == N_NBIN
    const int lane = threadIdx.x & 63;
    float a00 = 0.f, a01 = 0.f, a10 = 0.f, a11 = 0.f;
    #pragma unroll
    for (int s = 0; s < NSLC; ++s) {
        const int k  = s * N_NBIN + nb;
        const int st = (k == 0) ? 0 : bs[k - 1];
        const int en = bs[k];
        for (int j = st; j < en; ++j) {
            u32 p = stage[j];                    // wave-broadcast (L1)
            int e = (int)(p >> 17);
            float v0 = ef[(size_t)e * D_FEAT + lane];
            float v1 = ef[(size_t)e * D_FEAT + 64 + lane];
            if (p & 1u) { a10 += v0; a11 += v1; }
            else        { a00 += v0; a01 += v1; }
        }
    }
    const int n0 = nb * 2, n1 = nb * 2 + 1;
    const int c0 = cnt_n[n0], c1 = cnt_n[n1];
    const float s0 = (c0 > 0) ? rsqrtf((float)c0) : 0.f;
    const float s1 = (c1 > 0) ? rsqrtf((float)c1) : 0.f;
    a00 *= s0; a01 *= s0; a10 *= s1; a11 *= s1;
    out[(size_t)n0 * D_FEAT + lane]      = (a00 > 0.f) ? a00 : 0.f;
    out[(size_t)n0 * D_FEAT + 64 + lane] = (a01 > 0.f) ? a01 : 0.f;
    out[(size_t)n1 * D_FEAT + lane]      = (a10 > 0.f) ? a10 : 0.f;
    out[(size_t)n1 * D_FEAT + 64 + lane] = (a11 > 0.f) ? a11 : 0.f;
}

// ---------------------------------------------------------------------------
extern "C" void kernel_launch(void* const* d_in, const int* in_sizes, int n_in,
                              void* d_out, int out_size, void* d_ws, size_t ws_size,
                              hipStream_t stream)
{
    const float* x  = (const float*)d_in[0];   // fp32 (N,128)
    const float* W  = (const float*)d_in[1];   // fp32 (128,128)
    const float* b  = (const float*)d_in[2];   // fp32 (128,)
    const int* ni   = (const int*)d_in[3];     // (800000,) node_idx
    const int* ei   = (const int*)d_in[4];     // (800000,) edge_idx
    float* out = (float*)d_out;                // fp32 (N,128)

    // Workspace ~60.3 MB (r1 proved >=61.9 MB available).
    // Region A (51.2 MB): split writes xhi/xlo; ef aliases it after linear.
    // stage/bs/cnt_n live OUTSIDE region A (consumed until the last kernel).
    char* base = (char*)d_ws;
    u16*   xhi  = (u16*)base;                                  // 25.6 MB
    u16*   xlo  = (u16*)(base + (size_t)N_NODES * D_FEAT * 2); // 25.6 MB
    float* ef   = (float*)base;                                // aliases region A
    char* p = base + (size_t)N_NODES * D_FEAT * 4;             // end of region A
    int* bs     = (int*)p;   p += (size_t)BS_TOTAL * 4;        // 2.24 MB
    int* cnt_n  = (int*)p;   p += (size_t)N_NODES * 4;         // 0.4 MB (contig w/ bs)
    int* bsum   = (int*)p;   p += (size_t)((NBLK2 + 7) & ~7) * 4;
    u16* Whi    = (u16*)p;   p += (size_t)D_FEAT * D_FEAT * 2; // 32 KB
    u16* Wlo    = (u16*)p;   p += (size_t)D_FEAT * D_FEAT * 2; // 32 KB
    u32* stage  = (u32*)p;   p += (size_t)N_STAGE * 4;         // 6.4 MB
    float* xn   = out;   // xn staged in d_out (linear writes, n2e reads, e2n overwrites)

    const int nInc = (N_INC + 255) / 256;                      // 3125

    // bs and cnt_n are contiguous: one zero pass over both
    zero_int<<<(BS_TOTAL + N_NODES + 255) / 256, 256, 0, stream>>>(bs, BS_TOTAL + N_NODES);
    count2<<<nInc, 256, 0, stream>>>(ni, ei, cnt_n, bs);

    scanA<<<NBLK2, 256, 0, stream>>>(bs, bsum, BS_TOTAL);
    scanB<<<1, 256, 0, stream>>>(bsum, NBLK2);
    scanC<<<NBLK2, 256, 0, stream>>>(bs, bsum, BS_TOTAL);

    stage2<<<nInc, 256, 0, stream>>>(ni, ei, bs, stage);

    split_kernel<<<1024, 256, 0, stream>>>(x, xhi, xlo, N_NODES * D_FEAT);
    split_kernel<<<64, 256, 0, stream>>>(W, Whi, Wlo, D_FEAT * D_FEAT);

    linear_mfma<<<(N_WTILE + 3) / 4, 256, 0, stream>>>(
        xhi, xlo, Whi, Wlo, b, cnt_n, xn);

    n2e2<<<N_EDGES / 4, 256, 0, stream>>>(bs, stage, xn, ef);

    e2n2<<<N_NBIN / 4, 256, 0, stream>>>(bs, stage, cnt_n, ef, out);
}

// Round 5
// 555.164 us; speedup vs baseline: 1.4203x; 1.0274x over previous
//
#include <hip/hip_runtime.h>
#include <cstddef>

// Fixed problem instance (inputs fp32; probe-verified r8)
#define D_FEAT 128
static constexpr int N_NODES = 100000;
static constexpr int N_EDGES = 20000;
static constexpr int N_INC   = 800000;
static constexpr int N_WTILE = N_NODES / 16;               // 6250 16-row MFMA tiles

// Sliced staged-CSR (r11, proven 570us): per-(bin,slice) segments with
// slice = blockIdx%8 (empirical round-robin block->XCD) keep stage-write
// frontier lines single-XCD. Consume kernels read staged (e,n) directly.
// r12: gather kernels were issue-bound (e2n2: 3 VMEM/entry, VALU 27%,
// HBM 25% -> no wall). float2 row access = 1 load per entry per wave.
static constexpr int NSLC    = 8;
static constexpr int NB_SHIFT= 1;                           // 2 nodes / bin
static constexpr int N_NBIN  = N_NODES >> NB_SHIFT;         // 50000
static constexpr int NS_CNT  = NSLC * N_NBIN;               // 400000 node-side counters
static constexpr int ES_CNT  = NSLC * N_EDGES;              // 160000 edge-side counters
static constexpr int BS_TOTAL= NS_CNT + ES_CNT;             // 560000
static constexpr int NBLK2   = (BS_TOTAL + 255) / 256;      // 2188 scan blocks
static constexpr int N_STAGE = 2 * N_INC;                   // 1.6M staged entries

typedef unsigned short u16;
typedef unsigned int   u32;
typedef __attribute__((ext_vector_type(8))) short v8s;     // MFMA A/B frag (8 bf16)
typedef __attribute__((ext_vector_type(4))) float v4f;     // MFMA C/D frag + vec load
typedef __attribute__((ext_vector_type(4))) unsigned short v4u;

// ---------------------------------------------------------------------------
__global__ __launch_bounds__(256) void zero_int(int* __restrict__ p, int n)
{
    int i = blockIdx.x * 256 + threadIdx.x;
    if (i < n) p[i] = 0;
}

// 1) histogram: per-node degree (for rsqrt) + per-(bin,slice) counts.
// Per-edge degree is NOT counted: n2e derives |e| from its segment bounds.
__global__ __launch_bounds__(256) void count2(
    const int* __restrict__ ni, const int* __restrict__ ei,
    int* __restrict__ cnt_n, int* __restrict__ bs)
{
    int i = blockIdx.x * 256 + threadIdx.x;
    int s = blockIdx.x & 7;                       // must match stage2's mapping
    if (i < N_INC) {
        int n = ni[i], e = ei[i];
        atomicAdd(&cnt_n[n], 1);
        atomicAdd(&bs[s * N_NBIN + (n >> NB_SHIFT)], 1);
        atomicAdd(&bs[NS_CNT + s * N_EDGES + e], 1);
    }
}

// ---------------------------------------------------------------------------
// 2a) per-block exclusive scan IN PLACE
__global__ __launch_bounds__(256) void scanA(
    int* __restrict__ a, int* __restrict__ bsum, int n)
{
    __shared__ int sm[256];
    const int tid = threadIdx.x;
    const int i = blockIdx.x * 256 + tid;
    int v = (i < n) ? a[i] : 0;
    sm[tid] = v;
    __syncthreads();
    #pragma unroll
    for (int d = 1; d < 256; d <<= 1) {
        int t = (tid >= d) ? sm[tid - d] : 0;
        __syncthreads();
        sm[tid] += t;
        __syncthreads();
    }
    if (i < n) a[i] = sm[tid] - v;               // exclusive, block-local
    if (tid == 0) bsum[blockIdx.x] = sm[255];    // block total
}

// 2b) single-block exclusive scan of bsum[n]
__global__ __launch_bounds__(256) void scanB(int* __restrict__ a, int n)
{
    __shared__ int sm[256];
    __shared__ int carry;
    const int tid = threadIdx.x;
    if (tid == 0) carry = 0;
    __syncthreads();
    for (int base = 0; base < n; base += 256) {
        int i = base + tid;
        int v = (i < n) ? a[i] : 0;
        sm[tid] = v;
        __syncthreads();
        #pragma unroll
        for (int d = 1; d < 256; d <<= 1) {
            int t = (tid >= d) ? sm[tid - d] : 0;
            __syncthreads();
            sm[tid] += t;
            __syncthreads();
        }
        int excl = sm[tid] - v + carry;
        int total = sm[255];
        __syncthreads();
        if (tid == 0) carry += total;
        if (i < n) a[i] = excl;
        __syncthreads();
    }
}

// 2c) add block offsets in place
__global__ __launch_bounds__(256) void scanC(
    int* __restrict__ a, const int* __restrict__ bsum, int n)
{
    int i = blockIdx.x * 256 + threadIdx.x;
    if (i < n) a[i] += bsum[blockIdx.x];
}

// ---------------------------------------------------------------------------
// 3) stage: write packed (e,n) into per-(bin,slice) segments. Same grid and
// slice mapping as count2. After this kernel bs[k] = end of segment k =
// start of segment k+1 (exclusive-scan property).
__global__ __launch_bounds__(256) void stage2(
    const int* __restrict__ ni, const int* __restrict__ ei,
    int* __restrict__ bs, u32* __restrict__ stage)
{
    int i = blockIdx.x * 256 + threadIdx.x;
    int s = blockIdx.x & 7;
    if (i < N_INC) {
        int n = ni[i], e = ei[i];
        u32 p = ((u32)e << 17) | (u32)n;          // e<2^15, n<2^17
        stage[atomicAdd(&bs[s * N_NBIN + (n >> NB_SHIFT)], 1)] = p;
        stage[atomicAdd(&bs[NS_CNT + s * N_EDGES + e], 1)] = p;
    }
}

// ---------------------------------------------------------------------------
// 4a) Dekker split, float4-vectorized (G13): v = bf16(hi) + bf16(lo),
// residual ~2^-17 rel. n4 = element count / 4.
__global__ __launch_bounds__(256) void split_kernel(
    const float* __restrict__ in, u16* __restrict__ hi, u16* __restrict__ lo, int n4)
{
    for (int i = blockIdx.x * 256 + threadIdx.x; i < n4; i += gridDim.x * 256) {
        v4f v = *(const v4f*)(in + (size_t)i * 4);
        v4u h4, l4;
        #pragma unroll
        for (int c = 0; c < 4; ++c) {
            u32 uv = __float_as_uint(v[c]);
            u32 h  = (uv + 0x7FFFu + ((uv >> 16) & 1u)) & 0xFFFF0000u;  // bf16 RNE
            float r = v[c] - __uint_as_float(h);                        // exact
            u32 ur = __float_as_uint(r);
            u32 l  = ur + 0x7FFFu + ((ur >> 16) & 1u);
            h4[c] = (u16)(h >> 16);
            l4[c] = (u16)(l >> 16);
        }
        *(v4u*)(hi + (size_t)i * 4) = h4;
        *(v4u*)(lo + (size_t)i * 4) = l4;
    }
}

// ---------------------------------------------------------------------------
// 4b) xn = (x @ W^T + b) * rsqrt(deg_n), fp32-accurate via split-bf16 MFMA:
// x.W^T = xhi.Whi + xhi.Wlo + xlo.Whi  (lo.lo ~2^-18, dropped).
// Wave tile 16 rows x 128 cols; gemm_bt fragment pattern; C/D col=lane&15,
// row=quad*4+reg.  (unchanged, proven)
__global__ __launch_bounds__(256) void linear_mfma(
    const u16* __restrict__ xhi, const u16* __restrict__ xlo,
    const u16* __restrict__ Whi, const u16* __restrict__ Wlo,
    const float* __restrict__ bias, const int* __restrict__ cnt_n,
    float* __restrict__ xn)
{
    const int wave = threadIdx.x >> 6;
    const int lane = threadIdx.x & 63;
    const int rowBase = (blockIdx.x * 4 + wave) * 16;
    if (rowBase >= N_NODES) return;                 // tail waves idle (no barriers)
    const int m    = lane & 15;
    const int quad = lane >> 4;

    v4f acc[8];
    #pragma unroll
    for (int t = 0; t < 8; ++t) acc[t] = (v4f){0.f, 0.f, 0.f, 0.f};

    #pragma unroll
    for (int ks = 0; ks < 4; ++ks) {
        const int k0 = ks * 32 + quad * 8;
        const size_t axo = (size_t)(rowBase + m) * D_FEAT + k0;
        v8s ah = *(const v8s*)(xhi + axo);
        v8s al = *(const v8s*)(xlo + axo);
        #pragma unroll
        for (int t = 0; t < 8; ++t) {
            const size_t bo = (size_t)(t * 16 + m) * D_FEAT + k0;
            v8s bh = *(const v8s*)(Whi + bo);
            v8s bl = *(const v8s*)(Wlo + bo);
            acc[t] = __builtin_amdgcn_mfma_f32_16x16x32_bf16(ah, bh, acc[t], 0, 0, 0);
            acc[t] = __builtin_amdgcn_mfma_f32_16x16x32_bf16(ah, bl, acc[t], 0, 0, 0);
            acc[t] = __builtin_amdgcn_mfma_f32_16x16x32_bf16(al, bh, acc[t], 0, 0, 0);
        }
    }

    const int rq = rowBase + quad * 4;
    const int c0 = cnt_n[rq + 0], c1 = cnt_n[rq + 1];
    const int c2 = cnt_n[rq + 2], c3 = cnt_n[rq + 3];
    const float s0 = (c0 > 0) ? rsqrtf((float)c0) : 0.f;
    const float s1 = (c1 > 0) ? rsqrtf((float)c1) : 0.f;
    const float s2 = (c2 > 0) ? rsqrtf((float)c2) : 0.f;
    const float s3 = (c3 > 0) ? rsqrtf((float)c3) : 0.f;

    #pragma unroll
    for (int t = 0; t < 8; ++t) {
        const int col = t * 16 + m;
        const float bv = bias[col];
        float* o = xn + (size_t)rq * D_FEAT + col;
        o[0 * D_FEAT] = (acc[t][0] + bv) * s0;
        o[1 * D_FEAT] = (acc[t][1] + bv) * s1;
        o[2 * D_FEAT] = (acc[t][2] + bv) * s2;
        o[3 * D_FEAT] = (acc[t][3] + bv) * s3;
    }
}

// ---------------------------------------------------------------------------
// 5) per-edge gather from staged segments: ef[e,:] = (1/|e|) * sum xn[n,:]
// One wave per edge. r12: lane covers cols {2*lane, 2*lane+1} -> ONE dwordx2
// load per entry (512B/row/wave in one instruction). |e| from segment bounds.
__global__ __launch_bounds__(256) void n2e2(
    const int* __restrict__ bs, const u32* __restrict__ stage,
    const float* __restrict__ xn, float* __restrict__ ef)
{
    const int e    = blockIdx.x * 4 + (threadIdx.x >> 6);
    const int fo   = (threadIdx.x & 63) * 2;
    float a0 = 0.f, a1 = 0.f;
    int c = 0;
    #pragma unroll
    for (int s = 0; s < NSLC; ++s) {
        const int k  = NS_CNT + s * N_EDGES + e;
        const int st = bs[k - 1];                // k>=1 always (node-side precedes)
        const int en = bs[k];
        c += en - st;
        for (int j = st; j < en; ++j) {
            int n = (int)(stage[j] & 0x1FFFFu);  // wave-broadcast (L1)
            const float2 v = *(const float2*)(xn + (size_t)n * D_FEAT + fo);
            a0 += v.x;
            a1 += v.y;
        }
    }
    const float inv = (c > 0) ? (1.0f / (float)c) : 0.f;
    float2 o; o.x = a0 * inv; o.y = a1 * inv;
    *(float2*)(ef + (size_t)e * D_FEAT + fo) = o;
}

// ---------------------------------------------------------------------------
// 6) per-node-bin gather + finalize. One wave per 2-node bin; entry low bit
// (= n&1) selects accumulator pair (wave-uniform). float2 per entry.
__global__ __launch_bounds__(256) void e2n2(
    const int* __restrict__ bs, const u32* __restrict__ stage,
    const int* __restrict__ cnt_n, const float* __restrict__ ef,
    float* __restrict__ out)
{
    const int nb   = blockIdx.x * 4 + (threadIdx.x >> 6);   // 12500*4 == N_NBIN
    const int fo   = (threadIdx.x & 63) * 2;
    float a00 = 0.f, a01 = 0.f, a10 = 0.f, a11 = 0.f;
    #pragma unroll
    for (int s = 0; s < NSLC; ++s) {
        const int k  = s * N_NBIN + nb;
        const int st = (k == 0) ? 0 : bs[k - 1];
        const int en = bs[k];
        for (int j = st; j < en; ++j) {
            u32 p = stage[j];                    // wave-broadcast (L1)
            int e = (int)(p >> 17);
            const float2 v = *(const float2*)(ef + (size_t)e * D_FEAT + fo);
            if (p & 1u) { a10 += v.x; a11 += v.y; }
            else        { a00 += v.x; a01 += v.y; }
        }
    }
    const int n0 = nb * 2, n1 = nb * 2 + 1;
    const int c0 = cnt_n[n0], c1 = cnt_n[n1];
    const float s0 = (c0 > 0) ? rsqrtf((float)c0) : 0.f;
    const float s1 = (c1 > 0) ? rsqrtf((float)c1) : 0.f;
    a00 *= s0; a01 *= s0; a10 *= s1; a11 *= s1;
    float2 o0; o0.x = (a00 > 0.f) ? a00 : 0.f; o0.y = (a01 > 0.f) ? a01 : 0.f;
    float2 o1; o1.x = (a10 > 0.f) ? a10 : 0.f; o1.y = (a11 > 0.f) ? a11 : 0.f;
    *(float2*)(out + (size_t)n0 * D_FEAT + fo) = o0;
    *(float2*)(out + (size_t)n1 * D_FEAT + fo) = o1;
}

// ---------------------------------------------------------------------------
extern "C" void kernel_launch(void* const* d_in, const int* in_sizes, int n_in,
                              void* d_out, int out_size, void* d_ws, size_t ws_size,
                              hipStream_t stream)
{
    const float* x  = (const float*)d_in[0];   // fp32 (N,128)
    const float* W  = (const float*)d_in[1];   // fp32 (128,128)
    const float* b  = (const float*)d_in[2];   // fp32 (128,)
    const int* ni   = (const int*)d_in[3];     // (800000,) node_idx
    const int* ei   = (const int*)d_in[4];     // (800000,) edge_idx
    float* out = (float*)d_out;                // fp32 (N,128)

    // Workspace ~60.3 MB (r1 proved >=61.9 MB available).
    // Region A (51.2 MB): split writes xhi/xlo; ef aliases it after linear.
    // stage/bs/cnt_n live OUTSIDE region A (consumed until the last kernel).
    char* base = (char*)d_ws;
    u16*   xhi  = (u16*)base;                                  // 25.6 MB
    u16*   xlo  = (u16*)(base + (size_t)N_NODES * D_FEAT * 2); // 25.6 MB
    float* ef   = (float*)base;                                // aliases region A
    char* p = base + (size_t)N_NODES * D_FEAT * 4;             // end of region A
    int* bs     = (int*)p;   p += (size_t)BS_TOTAL * 4;        // 2.24 MB
    int* cnt_n  = (int*)p;   p += (size_t)N_NODES * 4;         // 0.4 MB (contig w/ bs)
    int* bsum   = (int*)p;   p += (size_t)((NBLK2 + 7) & ~7) * 4;
    u16* Whi    = (u16*)p;   p += (size_t)D_FEAT * D_FEAT * 2; // 32 KB
    u16* Wlo    = (u16*)p;   p += (size_t)D_FEAT * D_FEAT * 2; // 32 KB
    u32* stage  = (u32*)p;   p += (size_t)N_STAGE * 4;         // 6.4 MB
    float* xn   = out;   // xn staged in d_out (linear writes, n2e reads, e2n overwrites)

    const int nInc = (N_INC + 255) / 256;                      // 3125

    // bs and cnt_n are contiguous: one zero pass over both
    zero_int<<<(BS_TOTAL + N_NODES + 255) / 256, 256, 0, stream>>>(bs, BS_TOTAL + N_NODES);
    count2<<<nInc, 256, 0, stream>>>(ni, ei, cnt_n, bs);

    scanA<<<NBLK2, 256, 0, stream>>>(bs, bsum, BS_TOTAL);
    scanB<<<1, 256, 0, stream>>>(bsum, NBLK2);
    scanC<<<NBLK2, 256, 0, stream>>>(bs, bsum, BS_TOTAL);

    stage2<<<nInc, 256, 0, stream>>>(ni, ei, bs, stage);

    split_kernel<<<1024, 256, 0, stream>>>(x, xhi, xlo, N_NODES * D_FEAT / 4);
    split_kernel<<<16, 256, 0, stream>>>(W, Whi, Wlo, D_FEAT * D_FEAT / 4);

    linear_mfma<<<(N_WTILE + 3) / 4, 256, 0, stream>>>(
        xhi, xlo, Whi, Wlo, b, cnt_n, xn);

    n2e2<<<N_EDGES / 4, 256, 0, stream>>>(bs, stage, xn, ef);

    e2n2<<<N_NBIN / 4, 256, 0, stream>>>(bs, stage, cnt_n, ef, out);
}